// Round 3
// baseline (623.838 us; speedup 1.0000x reference)
//
#include <hip/hip_runtime.h>
#include <hip/hip_cooperative_groups.h>
#include <hip/hip_bf16.h>

namespace cg = cooperative_groups;

// Problem constants (from reference)
#define TT 128   // time points
#define DD 64    // state dim
#define HH 256   // f-net hidden
#define HK 128   // kernel-net hidden
#define JH (TT*HK)      // 16384 contraction dim for G1
#define HD (HK*DD)      // 8192
#define NCHUNK 32       // jh chunks of 512 (= 4 j's each)

// ===========================================================================
// Fused cooperative kernel: whole solve in one launch.
// Grid: 256 blocks x 256 threads (1 block/CU). 13 grid syncs total.
// ===========================================================================
union SMem {
    struct { float As[16 * 512]; float red[4][16][64]; } g1;       // 48 KB
    struct { float red[4][64]; float ys[DD]; float hs[HH]; float fs[DD]; } ff;
    struct { float Fs[16][64]; } mm;
    struct { float red[4][64]; } fin;
    struct { float tile[32][65]; } tr;
};

__global__ void __launch_bounds__(256)
fused_ide(const float* __restrict__ z0, const float* __restrict__ t,
          const float* __restrict__ W1, const float* __restrict__ b1,
          const float* __restrict__ W2, const float* __restrict__ b2,
          const float* __restrict__ Wk1, const float* __restrict__ bk1,
          const float* __restrict__ Wk2, const float* __restrict__ bk2,
          float* __restrict__ out,
          float* __restrict__ A, float* __restrict__ Wk2t,
          float* __restrict__ M, float* __restrict__ F,
          float* __restrict__ bF, float* __restrict__ G,
          float* __restrict__ P)
{
    cg::grid_group grid = cg::this_grid();
    __shared__ SMem sm;
    const int bid = blockIdx.x, tid = threadIdx.x;
    const float dt = t[1] - t[0];

    // ---------------- precompute A[i, j*HK+h] = w(i,j)*tanh(...) -----------
    {
        int gid = bid * 256 + tid;
        #pragma unroll 4
        for (int k = 0; k < 32; ++k) {
            int idx = gid + k * 65536;
            int h = idx & 127, j = (idx >> 7) & 127, i = idx >> 14;
            float w = (i == 0 || j > i) ? 0.f : dt * ((j == 0 || j == i) ? 0.5f : 1.0f);
            float v = tanhf(t[i] * Wk1[h] + t[j] * Wk1[HK + h] + bk1[h]);
            A[idx] = w * v;
        }
    }
    // ---------------- precompute Wk2t[e*HD + h*DD + d] = Wk2[h, d*DD+e] ----
    {
        int h = bid >> 1, dh = (bid & 1) * 32;
        for (int k = tid; k < 32 * 64; k += 256) {
            int d = k >> 6, e = k & 63;
            sm.tr.tile[d][e] = Wk2[(size_t)h * (DD * DD) + (size_t)(dh + d) * DD + e];
        }
        __syncthreads();
        for (int k = tid; k < 64 * 32; k += 256) {
            int e = k >> 5, d = k & 31;
            Wk2t[(size_t)e * HD + h * DD + dh + d] = sm.tr.tile[d][e];
        }
    }
    grid.sync();

    for (int it = 0; it < 3; ++it) {
        // ---- F phase: recompute y[j] from prev G, then f-MLP + bF --------
        if (bid < TT) {
            int j = bid, part = tid >> 6, d = tid & 63;
            if (it == 0) {
                if (tid < DD) sm.ff.ys[tid] = z0[tid];
            } else {
                float s = 0.f;
                if (j > 0) {
                    for (int jp = part; jp <= j; jp += 4) {
                        float w = (jp == 0 || jp == j) ? 0.5f : 1.0f;
                        s += w * G[jp * DD + d];
                    }
                }
                sm.ff.red[part][d] = s;
                __syncthreads();
                if (part == 0)
                    sm.ff.ys[d] = z0[d] + dt * (sm.ff.red[0][d] + sm.ff.red[1][d] +
                                                sm.ff.red[2][d] + sm.ff.red[3][d]);
            }
            __syncthreads();
            float acc = b1[tid];
            #pragma unroll 8
            for (int e = 0; e < DD; ++e) acc += sm.ff.ys[e] * W1[e * HH + tid];
            sm.ff.hs[tid] = tanhf(acc);
            __syncthreads();
            if (tid < DD) {
                float a = b2[tid];
                #pragma unroll 8
                for (int h = 0; h < HH; ++h) a += sm.ff.hs[h] * W2[h * DD + tid];
                sm.ff.fs[tid] = a;
                F[j * DD + tid] = a;
            }
            __syncthreads();
            if (tid < DD) {
                float a = 0.f;
                #pragma unroll 8
                for (int e = 0; e < DD; ++e) a += bk2[tid * DD + e] * sm.ff.fs[e];
                bF[j * DD + tid] = a;
            }
        }
        grid.sync();

        // ---- M phase: M[j, hd] = sum_e F[j,e] * Wk2t[e, hd] --------------
        {
            int hd = (bid & 31) * 256 + tid;
            int j0 = (bid >> 5) * 16;
            for (int k = tid; k < 16 * DD; k += 256) sm.mm.Fs[k >> 6][k & 63] = F[j0 * DD + k];
            __syncthreads();
            float acc[16];
            #pragma unroll
            for (int k = 0; k < 16; ++k) acc[k] = 0.f;
            const float* Wp = Wk2t + hd;
            for (int e = 0; e < DD; e += 8) {
                float w0 = Wp[(size_t)(e + 0) * HD];
                float w1 = Wp[(size_t)(e + 1) * HD];
                float w2 = Wp[(size_t)(e + 2) * HD];
                float w3 = Wp[(size_t)(e + 3) * HD];
                float w4 = Wp[(size_t)(e + 4) * HD];
                float w5 = Wp[(size_t)(e + 5) * HD];
                float w6 = Wp[(size_t)(e + 6) * HD];
                float w7 = Wp[(size_t)(e + 7) * HD];
                #pragma unroll
                for (int k = 0; k < 16; ++k) {
                    float4 f0 = *(const float4*)&sm.mm.Fs[k][e];
                    float4 f1 = *(const float4*)&sm.mm.Fs[k][e + 4];
                    acc[k] += f0.x * w0 + f0.y * w1 + f0.z * w2 + f0.w * w3
                            + f1.x * w4 + f1.y * w5 + f1.z * w6 + f1.w * w7;
                }
            }
            #pragma unroll
            for (int k = 0; k < 16; ++k) M[(size_t)(j0 + k) * HD + hd] = acc[k];
        }
        grid.sync();

        // ---- G1 phase: P[c, i, d] over 144 active triangular tiles -------
        // tiles: (itile in 0..7 of 16 rows) x (c in 0..min(4*itile+3, 31))
        if (bid < 144) {
            int itile = 0;
            while (2 * (itile + 1) * (itile + 2) <= bid) ++itile;
            int c = bid - 2 * itile * (itile + 1);
            const float* Ab = A + (size_t)itile * 16 * JH + c * 512;
            float4* As4 = (float4*)sm.g1.As;
            #pragma unroll
            for (int k = 0; k < 8; ++k) {
                int idx = tid + k * 256;          // 2048 float4
                int r = idx >> 7, q = idx & 127;
                As4[idx] = *(const float4*)(Ab + (size_t)r * JH + q * 4);
            }
            __syncthreads();
            float acc[16];
            #pragma unroll
            for (int r = 0; r < 16; ++r) acc[r] = 0.f;
            int sub = tid >> 6, d = tid & 63;
            const float* Mp = M + ((size_t)c * 512) * DD + d;
            int jl0 = sub * 128;
            for (int jl = jl0; jl < jl0 + 128; jl += 8) {
                float m0 = Mp[(size_t)(jl + 0) * DD];
                float m1 = Mp[(size_t)(jl + 1) * DD];
                float m2 = Mp[(size_t)(jl + 2) * DD];
                float m3 = Mp[(size_t)(jl + 3) * DD];
                float m4 = Mp[(size_t)(jl + 4) * DD];
                float m5 = Mp[(size_t)(jl + 5) * DD];
                float m6 = Mp[(size_t)(jl + 6) * DD];
                float m7 = Mp[(size_t)(jl + 7) * DD];
                #pragma unroll
                for (int r = 0; r < 16; ++r) {
                    float4 a0 = *(const float4*)&sm.g1.As[r * 512 + jl];
                    float4 a1 = *(const float4*)&sm.g1.As[r * 512 + jl + 4];
                    acc[r] += a0.x * m0 + a0.y * m1 + a0.z * m2 + a0.w * m3
                            + a1.x * m4 + a1.y * m5 + a1.z * m6 + a1.w * m7;
                }
            }
            #pragma unroll
            for (int r = 0; r < 16; ++r) sm.g1.red[sub][r][d] = acc[r];
            __syncthreads();
            if (sub == 0) {
                #pragma unroll
                for (int r = 0; r < 16; ++r) {
                    float v = sm.g1.red[0][r][d] + sm.g1.red[1][r][d] +
                              sm.g1.red[2][r][d] + sm.g1.red[3][r][d];
                    P[(size_t)c * (TT * DD) + (itile * 16 + r) * DD + d] = v;
                }
            }
        }
        grid.sync();

        // ---- Gfin phase: G[j] = sum_c P[c,j] + dt*trap(bF) ---------------
        if (bid < TT) {
            int j = bid, part = tid >> 6, d = tid & 63;
            float a = 0.f;
            int cmax = j >> 2;
            for (int c = part; c <= cmax; c += 4) a += P[(size_t)c * (TT * DD) + j * DD + d];
            if (j > 0) {
                float s = 0.f;
                for (int jp = part; jp <= j; jp += 4) {
                    float w = (jp == 0 || jp == j) ? 0.5f : 1.0f;
                    s += w * bF[jp * DD + d];
                }
                a += dt * s;
            }
            sm.fin.red[part][d] = a;
            __syncthreads();
            if (part == 0)
                G[j * DD + d] = sm.fin.red[0][d] + sm.fin.red[1][d] +
                                sm.fin.red[2][d] + sm.fin.red[3][d];
        }
        grid.sync();
    }

    // ---- output: y[T-1] = z0 + dt*trap(G over all rows) -------------------
    if (bid == 0) {
        int part = tid >> 6, d = tid & 63;
        float s = 0.f;
        for (int j = part; j < TT; j += 4) {
            float w = (j == 0 || j == TT - 1) ? 0.5f : 1.0f;
            s += w * G[j * DD + d];
        }
        sm.fin.red[part][d] = s;
        __syncthreads();
        if (part == 0)
            out[d] = z0[d] + dt * (sm.fin.red[0][d] + sm.fin.red[1][d] +
                                   sm.fin.red[2][d] + sm.fin.red[3][d]);
    }
}

// ===========================================================================
// Fallback multi-kernel path (round-2 proven) in case cooperative launch
// is rejected (returns error synchronously -> same decision every call).
// ===========================================================================
__global__ void k_A(const float* __restrict__ t, const float* __restrict__ Wk1,
                    const float* __restrict__ bk1, float* __restrict__ A) {
    int j = blockIdx.x, i = blockIdx.y, h = threadIdx.x;
    float dt = t[1] - t[0];
    float w;
    if (i == 0 || j > i) w = 0.f;
    else w = dt * ((j == 0 || j == i) ? 0.5f : 1.0f);
    float v = tanhf(t[i] * Wk1[h] + t[j] * Wk1[HK + h] + bk1[h]);
    A[((size_t)i * TT + j) * HK + h] = w * v;
}

__global__ void k_transpose_wk2(const float* __restrict__ Wk2, float* __restrict__ Wk2t) {
    __shared__ float s[64][65];
    int h = blockIdx.x;
    for (int k = threadIdx.x; k < DD * DD; k += 256) {
        int d = k >> 6, e = k & 63;
        s[d][e] = Wk2[(size_t)h * DD * DD + k];
    }
    __syncthreads();
    for (int k = threadIdx.x; k < DD * DD; k += 256) {
        int e = k >> 6, d = k & 63;
        Wk2t[(size_t)e * HD + h * DD + d] = s[d][e];
    }
}

__global__ void k_init_y(const float* __restrict__ z0, float* __restrict__ y) {
    int i = blockIdx.x, d = threadIdx.x;
    y[i * DD + d] = z0[d];
}

__global__ void k_f(const float* __restrict__ y, const float* __restrict__ W1,
                    const float* __restrict__ b1, const float* __restrict__ W2,
                    const float* __restrict__ b2, const float* __restrict__ bk2,
                    float* __restrict__ F, float* __restrict__ bF) {
    int j = blockIdx.x, t = threadIdx.x;
    __shared__ float ys[DD];
    __shared__ float hs[HH];
    __shared__ float fs[DD];
    if (t < DD) ys[t] = y[j * DD + t];
    __syncthreads();
    float acc = b1[t];
    #pragma unroll 8
    for (int e = 0; e < DD; ++e) acc += ys[e] * W1[e * HH + t];
    hs[t] = tanhf(acc);
    __syncthreads();
    if (t < DD) {
        float a = b2[t];
        #pragma unroll 8
        for (int h = 0; h < HH; ++h) a += hs[h] * W2[h * DD + t];
        fs[t] = a;
        F[j * DD + t] = a;
    }
    __syncthreads();
    if (t < DD) {
        float a = 0.f;
        #pragma unroll 8
        for (int e = 0; e < DD; ++e) a += bk2[t * DD + e] * fs[e];
        bF[j * DD + t] = a;
    }
}

__global__ void k_M(const float* __restrict__ F, const float* __restrict__ Wk2t,
                    float* __restrict__ M) {
    int t = threadIdx.x;
    int hd = blockIdx.x * 256 + t;
    int j0 = blockIdx.y * 16;
    __shared__ __attribute__((aligned(16))) float Fs[16][64];
    for (int k = t; k < 16 * DD; k += 256) Fs[k >> 6][k & 63] = F[j0 * DD + k];
    __syncthreads();
    float acc[16];
    #pragma unroll
    for (int k = 0; k < 16; ++k) acc[k] = 0.f;
    const float* Wp = Wk2t + hd;
    for (int e = 0; e < DD; e += 8) {
        float w0 = Wp[(size_t)(e+0) * HD];
        float w1 = Wp[(size_t)(e+1) * HD];
        float w2 = Wp[(size_t)(e+2) * HD];
        float w3 = Wp[(size_t)(e+3) * HD];
        float w4 = Wp[(size_t)(e+4) * HD];
        float w5 = Wp[(size_t)(e+5) * HD];
        float w6 = Wp[(size_t)(e+6) * HD];
        float w7 = Wp[(size_t)(e+7) * HD];
        #pragma unroll
        for (int k = 0; k < 16; ++k) {
            float4 f0 = *(const float4*)&Fs[k][e];
            float4 f1 = *(const float4*)&Fs[k][e + 4];
            acc[k] += f0.x*w0 + f0.y*w1 + f0.z*w2 + f0.w*w3
                    + f1.x*w4 + f1.y*w5 + f1.z*w6 + f1.w*w7;
        }
    }
    #pragma unroll
    for (int k = 0; k < 16; ++k) M[(size_t)(j0 + k) * HD + hd] = acc[k];
}

__global__ void k_G1(const float* __restrict__ A, const float* __restrict__ M,
                     float* __restrict__ P) {
    int itile = blockIdx.x, c = blockIdx.y;
    if (c > 2 * itile + 1) return;
    __shared__ __attribute__((aligned(16))) float As[8 * 512];
    __shared__ float red[4][8][64];
    int t = threadIdx.x, sub = t >> 6, d = t & 63;
    {
        const float* Ab = A + (size_t)itile * 8 * JH + c * 512;
        float4* As4 = (float4*)As;
        #pragma unroll
        for (int k = 0; k < 4; ++k) {
            int idx = t + k * 256;
            int r = idx >> 7, q = idx & 127;
            As4[r * 128 + q] = *(const float4*)(Ab + (size_t)r * JH + q * 4);
        }
    }
    __syncthreads();
    float acc[8] = {0.f, 0.f, 0.f, 0.f, 0.f, 0.f, 0.f, 0.f};
    const float* Mp = M + ((size_t)c * 512) * DD + d;
    int jl0 = sub * 128;
    for (int jl = jl0; jl < jl0 + 128; jl += 8) {
        float m0 = Mp[(size_t)(jl + 0) * DD];
        float m1 = Mp[(size_t)(jl + 1) * DD];
        float m2 = Mp[(size_t)(jl + 2) * DD];
        float m3 = Mp[(size_t)(jl + 3) * DD];
        float m4 = Mp[(size_t)(jl + 4) * DD];
        float m5 = Mp[(size_t)(jl + 5) * DD];
        float m6 = Mp[(size_t)(jl + 6) * DD];
        float m7 = Mp[(size_t)(jl + 7) * DD];
        #pragma unroll
        for (int r = 0; r < 8; ++r) {
            float4 a0 = *(const float4*)&As[r * 512 + jl];
            float4 a1 = *(const float4*)&As[r * 512 + jl + 4];
            acc[r] += a0.x*m0 + a0.y*m1 + a0.z*m2 + a0.w*m3
                    + a1.x*m4 + a1.y*m5 + a1.z*m6 + a1.w*m7;
        }
    }
    #pragma unroll
    for (int r = 0; r < 8; ++r) red[sub][r][d] = acc[r];
    __syncthreads();
    if (sub == 0) {
        #pragma unroll
        for (int r = 0; r < 8; ++r) {
            float v = red[0][r][d] + red[1][r][d] + red[2][r][d] + red[3][r][d];
            P[(size_t)c * (TT * DD) + (itile * 8 + r) * DD + d] = v;
        }
    }
}

__global__ void k_Gfin(const float* __restrict__ P, const float* __restrict__ bF,
                       const float* __restrict__ t, float* __restrict__ G) {
    int j = blockIdx.x, d = threadIdx.x;
    float dt = t[1] - t[0];
    float a = 0.f;
    int cmax = j >> 2;
    #pragma unroll 8
    for (int c = 0; c <= cmax; ++c) a += P[(size_t)c * (TT * DD) + j * DD + d];
    if (j > 0) {
        float s = 0.f;
        #pragma unroll 8
        for (int jp = 0; jp <= j; ++jp) {
            float wgt = (jp == 0 || jp == j) ? 0.5f : 1.0f;
            s += wgt * bF[jp * DD + d];
        }
        a += dt * s;
    }
    G[j * DD + d] = a;
}

__global__ void k_ynew(const float* __restrict__ G, const float* __restrict__ z0,
                       const float* __restrict__ t, float* __restrict__ ynew,
                       float* __restrict__ out_final) {
    int i = blockIdx.x, d = threadIdx.x;
    float dt = t[1] - t[0];
    float a = 0.f;
    if (i > 0) {
        float s = 0.f;
        #pragma unroll 8
        for (int j = 0; j <= i; ++j) {
            float wgt = (j == 0 || j == i) ? 0.5f : 1.0f;
            s += wgt * G[j * DD + d];
        }
        a = dt * s;
    }
    float v = z0[d] + a;
    ynew[i * DD + d] = v;
    if (out_final != nullptr && i == TT - 1) out_final[d] = v;
}

extern "C" void kernel_launch(void* const* d_in, const int* in_sizes, int n_in,
                              void* d_out, int out_size, void* d_ws, size_t ws_size,
                              hipStream_t stream) {
    const float* z0  = (const float*)d_in[0];
    const float* t   = (const float*)d_in[1];
    const float* W1  = (const float*)d_in[2];
    const float* b1  = (const float*)d_in[3];
    const float* W2  = (const float*)d_in[4];
    const float* b2  = (const float*)d_in[5];
    const float* Wk1 = (const float*)d_in[6];
    const float* bk1 = (const float*)d_in[7];
    const float* Wk2 = (const float*)d_in[8];
    const float* bk2 = (const float*)d_in[9];
    float* out = (float*)d_out;

    float* ws   = (float*)d_ws;
    float* A    = ws;                       // T*T*HK        = 2,097,152
    float* Wk2t = A    + (size_t)TT*TT*HK;  // HK*D*D        =   524,288
    float* M    = Wk2t + (size_t)HK*DD*DD;  // T*HK*D        = 1,048,576
    float* F    = M    + (size_t)TT*HK*DD;  // T*D
    float* bF   = F    + TT*DD;             // T*D
    float* G    = bF   + TT*DD;             // T*D
    float* P    = G    + TT*DD;             // 32*T*D        =   262,144
    float* yA   = P    + (size_t)NCHUNK*TT*DD;
    float* yB   = yA   + TT*DD;

    void* args[] = {
        (void*)&z0, (void*)&t, (void*)&W1, (void*)&b1, (void*)&W2, (void*)&b2,
        (void*)&Wk1, (void*)&bk1, (void*)&Wk2, (void*)&bk2, (void*)&out,
        (void*)&A, (void*)&Wk2t, (void*)&M, (void*)&F, (void*)&bF,
        (void*)&G, (void*)&P
    };
    hipError_t err = hipLaunchCooperativeKernel((const void*)fused_ide,
                                                dim3(256), dim3(256),
                                                args, 0, stream);
    if (err != hipSuccess) {
        // fallback: proven multi-kernel path
        k_A<<<dim3(TT, TT), HK, 0, stream>>>(t, Wk1, bk1, A);
        k_transpose_wk2<<<HK, 256, 0, stream>>>(Wk2, Wk2t);
        k_init_y<<<TT, DD, 0, stream>>>(z0, yA);
        float* ycur = yA;
        float* ynext = yB;
        for (int it = 0; it < 3; ++it) {
            k_f<<<TT, 256, 0, stream>>>(ycur, W1, b1, W2, b2, bk2, F, bF);
            k_M<<<dim3(HD / 256, TT / 16), 256, 0, stream>>>(F, Wk2t, M);
            k_G1<<<dim3(TT / 8, NCHUNK), 256, 0, stream>>>(A, M, P);
            k_Gfin<<<TT, DD, 0, stream>>>(P, bF, t, G);
            k_ynew<<<TT, DD, 0, stream>>>(G, z0, t, ynext, (it == 2) ? out : nullptr);
            float* tmp = ycur; ycur = ynext; ynext = tmp;
        }
    }
}

// Round 4
// 208.412 us; speedup vs baseline: 2.9933x; 2.9933x over previous
//
#include <hip/hip_runtime.h>
#include <hip/hip_bf16.h>

// Problem constants (from reference)
#define TT 128   // time points
#define DD 64    // state dim
#define HH 256   // f-net hidden
#define HK 128   // kernel-net hidden
#define JH (TT*HK)      // 16384 contraction dim for G1
#define HD (HK*DD)      // 8192
#define NCHUNK 64       // jh chunks of 256 (= 2 j's each)

// ---------------------------------------------------------------------------
// k_prep: blocks [0,1024): A[i, j*HK+h] = w(i,j)*tanh(t_i*Wk1[0,h]+t_j*Wk1[1,h]+bk1[h])
//         blocks [1024,1280): Wk2t[e*HD + h*DD + d] = Wk2[h, d*DD + e]
// ---------------------------------------------------------------------------
__global__ void __launch_bounds__(256)
k_prep(const float* __restrict__ t, const float* __restrict__ Wk1,
       const float* __restrict__ bk1, const float* __restrict__ Wk2,
       float* __restrict__ A, float* __restrict__ Wk2t) {
    __shared__ float tile[32][65];
    int b = blockIdx.x, tid = threadIdx.x;
    if (b < 1024) {
        float dt = t[1] - t[0];
        #pragma unroll
        for (int k = 0; k < 8; ++k) {
            int idx = b * 2048 + k * 256 + tid;
            int h = idx & 127, j = (idx >> 7) & 127, i = idx >> 14;
            float w = (i == 0 || j > i) ? 0.f : dt * ((j == 0 || j == i) ? 0.5f : 1.0f);
            float v = tanhf(t[i] * Wk1[h] + t[j] * Wk1[HK + h] + bk1[h]);
            A[idx] = w * v;
        }
    } else {
        int bb = b - 1024;
        int h = bb >> 1, dh = (bb & 1) * 32;
        for (int k = tid; k < 32 * 64; k += 256) {
            int d = k >> 6, e = k & 63;
            tile[d][e] = Wk2[(size_t)h * (DD * DD) + (size_t)(dh + d) * DD + e];
        }
        __syncthreads();
        for (int k = tid; k < 64 * 32; k += 256) {
            int e = k >> 5, d = k & 31;
            Wk2t[(size_t)e * HD + h * DD + dh + d] = tile[d][e];
        }
    }
}

// ---------------------------------------------------------------------------
// k_f: block j: y_j = z0 + dt*trap(G[0..j]) (it>0; else z0), then
//      F[j] = tanh(y_j@W1+b1)@W2+b2 ;  bF[j,d] = sum_e bk2[d*DD+e]*F[j,e]
// all 256 threads active in every stage (4-way partial + LDS reduce)
// ---------------------------------------------------------------------------
__global__ void __launch_bounds__(256)
k_f(const float* __restrict__ G, const float* __restrict__ z0,
    const float* __restrict__ t,
    const float* __restrict__ W1, const float* __restrict__ b1,
    const float* __restrict__ W2, const float* __restrict__ b2,
    const float* __restrict__ bk2,
    float* __restrict__ F, float* __restrict__ bF, int it) {
    int j = blockIdx.x, tid = threadIdx.x;
    int part = tid >> 6, d = tid & 63;
    __shared__ float red[4][64];
    __shared__ float ys[DD];
    __shared__ float hs[HH];
    __shared__ float fs[DD];
    float dt = t[1] - t[0];
    if (it == 0) {
        if (tid < DD) ys[tid] = z0[tid];
    } else {
        float s = 0.f;
        if (j > 0) {
            for (int jp = part; jp <= j; jp += 4) {
                float w = (jp == 0 || jp == j) ? 0.5f : 1.0f;
                s += w * G[jp * DD + d];
            }
        }
        red[part][d] = s;
        __syncthreads();
        if (part == 0)
            ys[d] = z0[d] + dt * (red[0][d] + red[1][d] + red[2][d] + red[3][d]);
    }
    __syncthreads();
    // layer 1: hs[tid] over 256 threads
    float acc = b1[tid];
    #pragma unroll 8
    for (int e = 0; e < DD; ++e) acc += ys[e] * W1[e * HH + tid];
    hs[tid] = tanhf(acc);
    __syncthreads();
    // layer 2: 4-way split over h
    {
        float s = 0.f;
        #pragma unroll 8
        for (int h = part * 64; h < part * 64 + 64; ++h) s += hs[h] * W2[h * DD + d];
        red[part][d] = s;
    }
    __syncthreads();
    if (part == 0) {
        float a = b2[d] + red[0][d] + red[1][d] + red[2][d] + red[3][d];
        fs[d] = a;
        F[j * DD + d] = a;
    }
    __syncthreads();
    // bF: 4-way split over e
    {
        float s = 0.f;
        #pragma unroll
        for (int e = part * 16; e < part * 16 + 16; ++e) s += bk2[d * DD + e] * fs[e];
        red[part][d] = s;
    }
    __syncthreads();
    if (part == 0)
        bF[j * DD + d] = red[0][d] + red[1][d] + red[2][d] + red[3][d];
}

// ---------------------------------------------------------------------------
// k_M: M[j*HD + hd] = sum_e F[j,e] * Wk2t[e*HD + hd]
// grid: (32 hd-chunks of 256, 16 j-chunks of 8), 256 threads, acc[8]
// ---------------------------------------------------------------------------
__global__ void __launch_bounds__(256)
k_M(const float* __restrict__ F, const float* __restrict__ Wk2t,
    float* __restrict__ M) {
    int tid = threadIdx.x;
    int hd = blockIdx.x * 256 + tid;
    int j0 = blockIdx.y * 8;
    __shared__ __attribute__((aligned(16))) float Fs[8][64];
    for (int k = tid; k < 8 * DD; k += 256) Fs[k >> 6][k & 63] = F[j0 * DD + k];
    __syncthreads();
    float acc[8];
    #pragma unroll
    for (int k = 0; k < 8; ++k) acc[k] = 0.f;
    const float* Wp = Wk2t + hd;
    for (int e = 0; e < DD; e += 8) {
        float w0 = Wp[(size_t)(e+0) * HD];
        float w1 = Wp[(size_t)(e+1) * HD];
        float w2 = Wp[(size_t)(e+2) * HD];
        float w3 = Wp[(size_t)(e+3) * HD];
        float w4 = Wp[(size_t)(e+4) * HD];
        float w5 = Wp[(size_t)(e+5) * HD];
        float w6 = Wp[(size_t)(e+6) * HD];
        float w7 = Wp[(size_t)(e+7) * HD];
        #pragma unroll
        for (int k = 0; k < 8; ++k) {
            float4 f0 = *(const float4*)&Fs[k][e];
            float4 f1 = *(const float4*)&Fs[k][e + 4];
            acc[k] += f0.x*w0 + f0.y*w1 + f0.z*w2 + f0.w*w3
                    + f1.x*w4 + f1.y*w5 + f1.z*w6 + f1.w*w7;
        }
    }
    #pragma unroll
    for (int k = 0; k < 8; ++k) M[(size_t)(j0 + k) * HD + hd] = acc[k];
}

// ---------------------------------------------------------------------------
// k_G1: P[c, i, d] = sum_{jh in chunk c (256 wide)} A[i, jh] * M[jh*DD + d]
// grid: (16 itiles of 8 rows, 64 chunks); active iff c <= 4*itile+3 (544 blocks)
// ---------------------------------------------------------------------------
__global__ void __launch_bounds__(256)
k_G1(const float* __restrict__ A, const float* __restrict__ M,
     float* __restrict__ P) {
    int itile = blockIdx.x, c = blockIdx.y;
    if (c > 4 * itile + 3) return;   // chunk j-range entirely above row range
    __shared__ __attribute__((aligned(16))) float As[8 * 256];   // 8 KB
    __shared__ float red[4][8][64];                              // 8 KB
    int tid = threadIdx.x, sub = tid >> 6, d = tid & 63;
    {
        const float* Ab = A + (size_t)itile * 8 * JH + c * 256;
        float4* As4 = (float4*)As;
        #pragma unroll
        for (int k = 0; k < 2; ++k) {
            int idx = tid + k * 256;          // 512 float4
            int r = idx >> 6, q = idx & 63;
            As4[idx] = *(const float4*)(Ab + (size_t)r * JH + q * 4);
        }
    }
    __syncthreads();
    float acc[8] = {0.f,0.f,0.f,0.f,0.f,0.f,0.f,0.f};
    const float* Mp = M + ((size_t)c * 256) * DD + d;
    int jl0 = sub * 64;
    for (int jl = jl0; jl < jl0 + 64; jl += 8) {
        float m0 = Mp[(size_t)(jl + 0) * DD];
        float m1 = Mp[(size_t)(jl + 1) * DD];
        float m2 = Mp[(size_t)(jl + 2) * DD];
        float m3 = Mp[(size_t)(jl + 3) * DD];
        float m4 = Mp[(size_t)(jl + 4) * DD];
        float m5 = Mp[(size_t)(jl + 5) * DD];
        float m6 = Mp[(size_t)(jl + 6) * DD];
        float m7 = Mp[(size_t)(jl + 7) * DD];
        #pragma unroll
        for (int r = 0; r < 8; ++r) {
            float4 a0 = *(const float4*)&As[r * 256 + jl];
            float4 a1 = *(const float4*)&As[r * 256 + jl + 4];
            acc[r] += a0.x*m0 + a0.y*m1 + a0.z*m2 + a0.w*m3
                    + a1.x*m4 + a1.y*m5 + a1.z*m6 + a1.w*m7;
        }
    }
    #pragma unroll
    for (int r = 0; r < 8; ++r) red[sub][r][d] = acc[r];
    __syncthreads();
    if (sub == 0) {
        #pragma unroll
        for (int r = 0; r < 8; ++r) {
            float v = red[0][r][d] + red[1][r][d] + red[2][r][d] + red[3][r][d];
            P[(size_t)c * (TT * DD) + (itile * 8 + r) * DD + d] = v;
        }
    }
}

// ---------------------------------------------------------------------------
// k_Gfin: G[j,d] = sum_{c<=j>>1} P[c,j,d] + dt * trap(bF[0..j], d)
// 256 threads, 4-way partial + LDS reduce
// ---------------------------------------------------------------------------
__global__ void __launch_bounds__(256)
k_Gfin(const float* __restrict__ P, const float* __restrict__ bF,
       const float* __restrict__ t, float* __restrict__ G) {
    int j = blockIdx.x, tid = threadIdx.x;
    int part = tid >> 6, d = tid & 63;
    __shared__ float red[4][64];
    float dt = t[1] - t[0];
    float a = 0.f;
    int cmax = j >> 1;
    for (int c = part; c <= cmax; c += 4) a += P[(size_t)c * (TT * DD) + j * DD + d];
    if (j > 0) {
        float s = 0.f;
        for (int jp = part; jp <= j; jp += 4) {
            float w = (jp == 0 || jp == j) ? 0.5f : 1.0f;
            s += w * bF[jp * DD + d];
        }
        a += dt * s;
    }
    red[part][d] = a;
    __syncthreads();
    if (part == 0)
        G[j * DD + d] = red[0][d] + red[1][d] + red[2][d] + red[3][d];
}

// ---------------------------------------------------------------------------
// k_out: out[d] = z0[d] + dt * trap(G[0..T-1], d)
// ---------------------------------------------------------------------------
__global__ void __launch_bounds__(256)
k_out(const float* __restrict__ G, const float* __restrict__ z0,
      const float* __restrict__ t, float* __restrict__ out) {
    int tid = threadIdx.x, part = tid >> 6, d = tid & 63;
    __shared__ float red[4][64];
    float dt = t[1] - t[0];
    float s = 0.f;
    for (int j = part; j < TT; j += 4) {
        float w = (j == 0 || j == TT - 1) ? 0.5f : 1.0f;
        s += w * G[j * DD + d];
    }
    red[part][d] = s;
    __syncthreads();
    if (part == 0)
        out[d] = z0[d] + dt * (red[0][d] + red[1][d] + red[2][d] + red[3][d]);
}

extern "C" void kernel_launch(void* const* d_in, const int* in_sizes, int n_in,
                              void* d_out, int out_size, void* d_ws, size_t ws_size,
                              hipStream_t stream) {
    const float* z0  = (const float*)d_in[0];
    const float* t   = (const float*)d_in[1];
    const float* W1  = (const float*)d_in[2];
    const float* b1  = (const float*)d_in[3];
    const float* W2  = (const float*)d_in[4];
    const float* b2  = (const float*)d_in[5];
    const float* Wk1 = (const float*)d_in[6];
    const float* bk1 = (const float*)d_in[7];
    const float* Wk2 = (const float*)d_in[8];
    const float* bk2 = (const float*)d_in[9];
    float* out = (float*)d_out;

    float* ws   = (float*)d_ws;
    float* A    = ws;                       // T*T*HK          = 2,097,152
    float* Wk2t = A    + (size_t)TT*TT*HK;  // HK*D*D          =   524,288
    float* M    = Wk2t + (size_t)HK*DD*DD;  // T*HK*D          = 1,048,576
    float* F    = M    + (size_t)TT*HK*DD;  // T*D
    float* bF   = F    + TT*DD;             // T*D
    float* G    = bF   + TT*DD;             // T*D
    float* P    = G    + TT*DD;             // 64*T*D          =   524,288

    k_prep<<<1280, 256, 0, stream>>>(t, Wk1, bk1, Wk2, A, Wk2t);

    for (int it = 0; it < 3; ++it) {
        k_f<<<TT, 256, 0, stream>>>(G, z0, t, W1, b1, W2, b2, bk2, F, bF, it);
        k_M<<<dim3(32, 16), 256, 0, stream>>>(F, Wk2t, M);
        k_G1<<<dim3(16, NCHUNK), 256, 0, stream>>>(A, M, P);
        k_Gfin<<<TT, 256, 0, stream>>>(P, bF, t, G);
    }
    k_out<<<1, 256, 0, stream>>>(G, z0, t, out);
}